// Round 6
// baseline (142.804 us; speedup 1.0000x reference)
//
#include <hip/hip_runtime.h>

// Static config (matches reference)
#define T_Q 8
#define H_Q 16
#define W_Q 16
#define HEADS 8
#define QDIM 64
#define QTOK (T_Q * H_Q * W_Q)   // 2048
#define KTOK 2048                 // T_K*H_K*W_K
#define REL_STRIDE 64             // padded rel row (floats): 40 used + 24 zero

typedef float f32x4 __attribute__((ext_vector_type(4)));

// ---------------- Kernel 1: precompute rel[row][0..39] into d_ws ------------
// rel[0..15]=rel_h, [16..31]=rel_w, [32..39]=rel_t. One row per wave.
__global__ __launch_bounds__(256)
void rel_precompute_kernel(const float* __restrict__ query,  // [rows, QDIM]
                           const float* __restrict__ hemb,   // [31, QDIM]
                           const float* __restrict__ wemb,   // [31, QDIM]
                           const float* __restrict__ temb,   // [15, QDIM]
                           float* __restrict__ relws)        // [rows, REL_STRIDE]
{
    const int tid  = threadIdx.x;
    const int wid  = tid >> 6;
    const int lane = tid & 63;
    const int row  = blockIdx.x * 4 + wid;
    const int qtok = row & (QTOK - 1);
    const int t = (qtok >> 8) & 7;
    const int h = (qtok >> 4) & 15;
    const int w = qtok & 15;

    __shared__ float q_s[4][QDIM];
    q_s[wid][lane] = query[(size_t)row * QDIM + lane];
    __syncthreads();

    float val = 0.f;
    if (lane < 40) {
        const float* emb;
        if (lane < 16) {
            emb = hemb + (size_t)(h - lane + 15) * QDIM;          // dist = h - hk + 15
        } else if (lane < 32) {
            emb = wemb + (size_t)(w - (lane - 16) + 15) * QDIM;   // dist = w - wk + 15
        } else {
            emb = temb + (size_t)(t - (lane - 32) + 7) * QDIM;    // dist = t - tk + 7
        }
        float a0 = 0.f, a1 = 0.f, a2 = 0.f, a3 = 0.f;
        #pragma unroll
        for (int c = 0; c < QDIM; c += 4) {
            f32x4 e  = *reinterpret_cast<const f32x4*>(emb + c);
            f32x4 qv = *reinterpret_cast<const f32x4*>(&q_s[wid][c]);
            a0 += qv.x * e.x;
            a1 += qv.y * e.y;
            a2 += qv.z * e.z;
            a3 += qv.w * e.w;
        }
        val = (a0 + a1) + (a2 + a3);
    }
    // All 64 lanes write (pad lanes write 0) so kernel 2 can bulk-load 256 B.
    relws[(size_t)row * REL_STRIDE + lane] = val;
}

// ---------------- Kernel 2: pure stream with precomputed rel ----------------
// R3's proven lockstep structure; prologue reduced to one global_load_lds of
// the LLC-hot rel row, fully hidden under the hoisted stream loads.
__global__ __launch_bounds__(256)
void relpos_stream_kernel(const float* __restrict__ scores,  // [rows, KTOK]
                          const float* __restrict__ relws,   // [rows, REL_STRIDE]
                          float* __restrict__ out)           // [rows, KTOK]
{
    const int tid  = threadIdx.x;
    const int wid  = tid >> 6;          // wave id 0..3
    const int lane = tid & 63;
    const int row  = blockIdx.x * 4 + wid;

    __shared__ float rel[4][REL_STRIDE];

    // ---- Hoisted stream loads: 8 x NT float4, independent of the prologue.
    const size_t base = (size_t)row * KTOK + lane * 4;
    f32x4 s0 = __builtin_nontemporal_load(reinterpret_cast<const f32x4*>(scores + base + 0 * 256));
    f32x4 s1 = __builtin_nontemporal_load(reinterpret_cast<const f32x4*>(scores + base + 1 * 256));
    f32x4 s2 = __builtin_nontemporal_load(reinterpret_cast<const f32x4*>(scores + base + 2 * 256));
    f32x4 s3 = __builtin_nontemporal_load(reinterpret_cast<const f32x4*>(scores + base + 3 * 256));
    f32x4 s4 = __builtin_nontemporal_load(reinterpret_cast<const f32x4*>(scores + base + 4 * 256));
    f32x4 s5 = __builtin_nontemporal_load(reinterpret_cast<const f32x4*>(scores + base + 5 * 256));
    f32x4 s6 = __builtin_nontemporal_load(reinterpret_cast<const f32x4*>(scores + base + 6 * 256));
    f32x4 s7 = __builtin_nontemporal_load(reinterpret_cast<const f32x4*>(scores + base + 7 * 256));

    // ---- rel row: global -> LDS direct (wave-uniform base + lane*4), 256 B.
    __builtin_amdgcn_global_load_lds(
        reinterpret_cast<const unsigned int*>(relws + (size_t)row * REL_STRIDE + lane),
        reinterpret_cast<unsigned int*>(&rel[wid][0]), 4, 0, 0);
    __syncthreads();   // drains rel + stream loads; rel (LLC) lands long before streams

    // ---- Per-lane invariant rel lookups.
    const float rh   = rel[wid][lane >> 2];
    const int   wk0  = (lane & 3) * 4;
    const float add0 = rh + rel[wid][16 + wk0 + 0];
    const float add1 = rh + rel[wid][16 + wk0 + 1];
    const float add2 = rh + rel[wid][16 + wk0 + 2];
    const float add3 = rh + rel[wid][16 + wk0 + 3];
    float rt[8];
    #pragma unroll
    for (int it = 0; it < 8; ++it) rt[it] = rel[wid][32 + it];

    // ---- Combine + NT stores (data already in registers).
    f32x4 o;
    o.x = s0.x + add0 + rt[0]; o.y = s0.y + add1 + rt[0]; o.z = s0.z + add2 + rt[0]; o.w = s0.w + add3 + rt[0];
    __builtin_nontemporal_store(o, reinterpret_cast<f32x4*>(out + base + 0 * 256));
    o.x = s1.x + add0 + rt[1]; o.y = s1.y + add1 + rt[1]; o.z = s1.z + add2 + rt[1]; o.w = s1.w + add3 + rt[1];
    __builtin_nontemporal_store(o, reinterpret_cast<f32x4*>(out + base + 1 * 256));
    o.x = s2.x + add0 + rt[2]; o.y = s2.y + add1 + rt[2]; o.z = s2.z + add2 + rt[2]; o.w = s2.w + add3 + rt[2];
    __builtin_nontemporal_store(o, reinterpret_cast<f32x4*>(out + base + 2 * 256));
    o.x = s3.x + add0 + rt[3]; o.y = s3.y + add1 + rt[3]; o.z = s3.z + add2 + rt[3]; o.w = s3.w + add3 + rt[3];
    __builtin_nontemporal_store(o, reinterpret_cast<f32x4*>(out + base + 3 * 256));
    o.x = s4.x + add0 + rt[4]; o.y = s4.y + add1 + rt[4]; o.z = s4.z + add2 + rt[4]; o.w = s4.w + add3 + rt[4];
    __builtin_nontemporal_store(o, reinterpret_cast<f32x4*>(out + base + 4 * 256));
    o.x = s5.x + add0 + rt[5]; o.y = s5.y + add1 + rt[5]; o.z = s5.z + add2 + rt[5]; o.w = s5.w + add3 + rt[5];
    __builtin_nontemporal_store(o, reinterpret_cast<f32x4*>(out + base + 5 * 256));
    o.x = s6.x + add0 + rt[6]; o.y = s6.y + add1 + rt[6]; o.z = s6.z + add2 + rt[6]; o.w = s6.w + add3 + rt[6];
    __builtin_nontemporal_store(o, reinterpret_cast<f32x4*>(out + base + 6 * 256));
    o.x = s7.x + add0 + rt[7]; o.y = s7.y + add1 + rt[7]; o.z = s7.z + add2 + rt[7]; o.w = s7.w + add3 + rt[7];
    __builtin_nontemporal_store(o, reinterpret_cast<f32x4*>(out + base + 7 * 256));
}

extern "C" void kernel_launch(void* const* d_in, const int* in_sizes, int n_in,
                              void* d_out, int out_size, void* d_ws, size_t ws_size,
                              hipStream_t stream) {
    const float* query  = (const float*)d_in[0];  // [2,8,2048,64]
    const float* scores = (const float*)d_in[1];  // [2,8,2048,2048]
    const float* hemb   = (const float*)d_in[2];  // [31,64]
    const float* wemb   = (const float*)d_in[3];  // [31,64]
    const float* temb   = (const float*)d_in[4];  // [15,64]
    float* out = (float*)d_out;
    float* relws = (float*)d_ws;                  // [rows, REL_STRIDE] = 8 MB

    const int B = in_sizes[0] / (HEADS * QTOK * QDIM);   // = 2
    const int rows = B * HEADS * QTOK;                    // 32768

    rel_precompute_kernel<<<rows / 4, 256, 0, stream>>>(query, hemb, wemb, temb, relws);
    relpos_stream_kernel<<<rows / 4, 256, 0, stream>>>(scores, relws, out);
}

// Round 7
// 103.141 us; speedup vs baseline: 1.3846x; 1.3846x over previous
//
#include <hip/hip_runtime.h>

// Static config (matches reference)
#define T_Q 8
#define H_Q 16
#define W_Q 16
#define HEADS 8
#define QDIM 64
#define QTOK (T_Q * H_Q * W_Q)   // 2048
#define KTOK 2048                 // T_K*H_K*W_K

typedef float f32x4 __attribute__((ext_vector_type(4)));

// R3's proven lockstep structure, amortized: each wave handles TWO rows.
// One barrier-drain bubble + one prologue per 64 KB streamed (was 32 KB).
// Block = 256 threads = 4 waves = 8 rows.
__global__ __launch_bounds__(256)
void relpos_fused_kernel(const float* __restrict__ query,   // [B*H*QTOK, QDIM]
                         const float* __restrict__ scores,  // [B*H*QTOK, KTOK]
                         const float* __restrict__ hemb,    // [31, QDIM]
                         const float* __restrict__ wemb,    // [31, QDIM]
                         const float* __restrict__ temb,    // [15, QDIM]
                         float* __restrict__ out)           // [B*H*QTOK, KTOK]
{
    const int tid  = threadIdx.x;
    const int wid  = tid >> 6;          // wave id 0..3
    const int lane = tid & 63;
    const int r0   = blockIdx.x * 8 + wid * 2;   // this wave's rows: r0, r0+1
    const int r1   = r0 + 1;

    __shared__ float q_s[8][QDIM];
    __shared__ float rel[8][40];        // [0..15]=rel_h, [16..31]=rel_w, [32..39]=rel_t

    // ---- Hoisted stream loads: 16 x NT float4 (8 per row), oldest-first.
    const size_t base0 = (size_t)r0 * KTOK + lane * 4;
    const size_t base1 = (size_t)r1 * KTOK + lane * 4;
    f32x4 s[16];
    #pragma unroll
    for (int it = 0; it < 8; ++it)
        s[it] = __builtin_nontemporal_load(
            reinterpret_cast<const f32x4*>(scores + base0 + it * 256));
    #pragma unroll
    for (int it = 0; it < 8; ++it)
        s[8 + it] = __builtin_nontemporal_load(
            reinterpret_cast<const f32x4*>(scores + base1 + it * 256));

    // ---- q rows: global -> LDS direct (wave-uniform base + lane*4).
    __builtin_amdgcn_global_load_lds(
        reinterpret_cast<const unsigned int*>(query + (size_t)r0 * QDIM + lane),
        reinterpret_cast<unsigned int*>(&q_s[wid * 2][0]), 4, 0, 0);
    __builtin_amdgcn_global_load_lds(
        reinterpret_cast<const unsigned int*>(query + (size_t)r1 * QDIM + lane),
        reinterpret_cast<unsigned int*>(&q_s[wid * 2 + 1][0]), 4, 0, 0);
    __syncthreads();   // one drain per 64 KB streamed

    // ---- Lanes 0..39 compute rel for both rows (emb rows are L1-hot).
    if (lane < 40) {
        #pragma unroll
        for (int rr = 0; rr < 2; ++rr) {
            const int row  = r0 + rr;
            const int qtok = row & (QTOK - 1);
            const int t = (qtok >> 8) & 7;
            const int h = (qtok >> 4) & 15;
            const int w = qtok & 15;
            const float* emb;
            if (lane < 16) {
                emb = hemb + (size_t)(h - lane + 15) * QDIM;          // dist = h - hk + 15
            } else if (lane < 32) {
                emb = wemb + (size_t)(w - (lane - 16) + 15) * QDIM;   // dist = w - wk + 15
            } else {
                emb = temb + (size_t)(t - (lane - 32) + 7) * QDIM;    // dist = t - tk + 7
            }
            float a0 = 0.f, a1 = 0.f, a2 = 0.f, a3 = 0.f;
            #pragma unroll
            for (int c = 0; c < QDIM; c += 4) {
                f32x4 e  = *reinterpret_cast<const f32x4*>(emb + c);
                f32x4 qv = *reinterpret_cast<const f32x4*>(&q_s[wid * 2 + rr][c]);
                a0 += qv.x * e.x;
                a1 += qv.y * e.y;
                a2 += qv.z * e.z;
                a3 += qv.w * e.w;
            }
            rel[wid * 2 + rr][lane] = (a0 + a1) + (a2 + a3);
        }
    }
    __syncthreads();

    // ---- Epilogue per row: invariant rel lookups + combine + NT stores.
    const int wk0 = (lane & 3) * 4;
    #pragma unroll
    for (int rr = 0; rr < 2; ++rr) {
        const float* rl = rel[wid * 2 + rr];
        const float rh   = rl[lane >> 2];
        const float add0 = rh + rl[16 + wk0 + 0];
        const float add1 = rh + rl[16 + wk0 + 1];
        const float add2 = rh + rl[16 + wk0 + 2];
        const float add3 = rh + rl[16 + wk0 + 3];
        const size_t base = rr ? base1 : base0;
        #pragma unroll
        for (int it = 0; it < 8; ++it) {
            const float rt = rl[32 + it];
            const f32x4 sv = s[rr * 8 + it];
            f32x4 o;
            o.x = sv.x + add0 + rt;
            o.y = sv.y + add1 + rt;
            o.z = sv.z + add2 + rt;
            o.w = sv.w + add3 + rt;
            __builtin_nontemporal_store(o,
                reinterpret_cast<f32x4*>(out + base + it * 256));
        }
    }
}

extern "C" void kernel_launch(void* const* d_in, const int* in_sizes, int n_in,
                              void* d_out, int out_size, void* d_ws, size_t ws_size,
                              hipStream_t stream) {
    const float* query  = (const float*)d_in[0];  // [2,8,2048,64]
    const float* scores = (const float*)d_in[1];  // [2,8,2048,2048]
    const float* hemb   = (const float*)d_in[2];  // [31,64]
    const float* wemb   = (const float*)d_in[3];  // [31,64]
    const float* temb   = (const float*)d_in[4];  // [15,64]
    float* out = (float*)d_out;

    const int B = in_sizes[0] / (HEADS * QTOK * QDIM);   // = 2
    const int rows = B * HEADS * QTOK;                    // 32768

    relpos_fused_kernel<<<rows / 8, 256, 0, stream>>>(query, scores, hemb, wemb, temb, out);
}

// Round 8
// 100.448 us; speedup vs baseline: 1.4217x; 1.0268x over previous
//
#include <hip/hip_runtime.h>

// Static config (matches reference)
#define T_Q 8
#define H_Q 16
#define W_Q 16
#define HEADS 8
#define QDIM 64
#define QTOK (T_Q * H_Q * W_Q)   // 2048
#define KTOK 2048                 // T_K*H_K*W_K

typedef float f32x4 __attribute__((ext_vector_type(4)));

// R3's proven per-wave structure (one row per wave, hoisted NT stream loads,
// global_load_lds q, two barriers) with an 8-wave (512-thread) block:
// one drain bubble per 64 KB streamed, per-wave VGPR unchanged.
__global__ __launch_bounds__(512)
void relpos_fused_kernel(const float* __restrict__ query,   // [B*H*QTOK, QDIM]
                         const float* __restrict__ scores,  // [B*H*QTOK, KTOK]
                         const float* __restrict__ hemb,    // [31, QDIM]
                         const float* __restrict__ wemb,    // [31, QDIM]
                         const float* __restrict__ temb,    // [15, QDIM]
                         float* __restrict__ out)           // [B*H*QTOK, KTOK]
{
    const int tid  = threadIdx.x;
    const int wid  = tid >> 6;          // wave id 0..7
    const int lane = tid & 63;
    const int row  = blockIdx.x * 8 + wid;
    const int qtok = row & (QTOK - 1);
    const int t = (qtok >> 8) & 7;
    const int h = (qtok >> 4) & 15;
    const int w = qtok & 15;

    __shared__ float q_s[8][QDIM];
    __shared__ float rel[8][40];        // [0..15]=rel_h, [16..31]=rel_w, [32..39]=rel_t

    // ---- Hoisted stream loads: 8 x NT float4, independent of the prologue.
    const size_t base = (size_t)row * KTOK + lane * 4;
    f32x4 s0 = __builtin_nontemporal_load(reinterpret_cast<const f32x4*>(scores + base + 0 * 256));
    f32x4 s1 = __builtin_nontemporal_load(reinterpret_cast<const f32x4*>(scores + base + 1 * 256));
    f32x4 s2 = __builtin_nontemporal_load(reinterpret_cast<const f32x4*>(scores + base + 2 * 256));
    f32x4 s3 = __builtin_nontemporal_load(reinterpret_cast<const f32x4*>(scores + base + 3 * 256));
    f32x4 s4 = __builtin_nontemporal_load(reinterpret_cast<const f32x4*>(scores + base + 4 * 256));
    f32x4 s5 = __builtin_nontemporal_load(reinterpret_cast<const f32x4*>(scores + base + 5 * 256));
    f32x4 s6 = __builtin_nontemporal_load(reinterpret_cast<const f32x4*>(scores + base + 6 * 256));
    f32x4 s7 = __builtin_nontemporal_load(reinterpret_cast<const f32x4*>(scores + base + 7 * 256));

    // ---- q row: global -> LDS direct (wave-uniform base + lane*4).
    __builtin_amdgcn_global_load_lds(
        reinterpret_cast<const unsigned int*>(query + (size_t)row * QDIM + lane),
        reinterpret_cast<unsigned int*>(&q_s[wid][0]), 4, 0, 0);
    __syncthreads();   // drains q + stream loads; stream BW time hides q latency

    // ---- Lanes 0..39 of EACH wave compute that wave's 40 rel values.
    if (lane < 40) {
        const float* emb;
        if (lane < 16) {
            emb = hemb + (size_t)(h - lane + 15) * QDIM;          // dist = h - hk + 15
        } else if (lane < 32) {
            emb = wemb + (size_t)(w - (lane - 16) + 15) * QDIM;   // dist = w - wk + 15
        } else {
            emb = temb + (size_t)(t - (lane - 32) + 7) * QDIM;    // dist = t - tk + 7
        }
        float a0 = 0.f, a1 = 0.f, a2 = 0.f, a3 = 0.f;
        #pragma unroll
        for (int c = 0; c < QDIM; c += 4) {
            f32x4 e  = *reinterpret_cast<const f32x4*>(emb + c);
            f32x4 qv = *reinterpret_cast<const f32x4*>(&q_s[wid][c]);
            a0 += qv.x * e.x;
            a1 += qv.y * e.y;
            a2 += qv.z * e.z;
            a3 += qv.w * e.w;
        }
        rel[wid][lane] = (a0 + a1) + (a2 + a3);
    }
    __syncthreads();

    // ---- Per-lane invariant rel lookups.
    const float rh   = rel[wid][lane >> 2];
    const int   wk0  = (lane & 3) * 4;
    const float add0 = rh + rel[wid][16 + wk0 + 0];
    const float add1 = rh + rel[wid][16 + wk0 + 1];
    const float add2 = rh + rel[wid][16 + wk0 + 2];
    const float add3 = rh + rel[wid][16 + wk0 + 3];
    float rt[8];
    #pragma unroll
    for (int it = 0; it < 8; ++it) rt[it] = rel[wid][32 + it];

    // ---- Combine + NT stores (data already in registers).
    f32x4 o;
    o.x = s0.x + add0 + rt[0]; o.y = s0.y + add1 + rt[0]; o.z = s0.z + add2 + rt[0]; o.w = s0.w + add3 + rt[0];
    __builtin_nontemporal_store(o, reinterpret_cast<f32x4*>(out + base + 0 * 256));
    o.x = s1.x + add0 + rt[1]; o.y = s1.y + add1 + rt[1]; o.z = s1.z + add2 + rt[1]; o.w = s1.w + add3 + rt[1];
    __builtin_nontemporal_store(o, reinterpret_cast<f32x4*>(out + base + 1 * 256));
    o.x = s2.x + add0 + rt[2]; o.y = s2.y + add1 + rt[2]; o.z = s2.z + add2 + rt[2]; o.w = s2.w + add3 + rt[2];
    __builtin_nontemporal_store(o, reinterpret_cast<f32x4*>(out + base + 2 * 256));
    o.x = s3.x + add0 + rt[3]; o.y = s3.y + add1 + rt[3]; o.z = s3.z + add2 + rt[3]; o.w = s3.w + add3 + rt[3];
    __builtin_nontemporal_store(o, reinterpret_cast<f32x4*>(out + base + 3 * 256));
    o.x = s4.x + add0 + rt[4]; o.y = s4.y + add1 + rt[4]; o.z = s4.z + add2 + rt[4]; o.w = s4.w + add3 + rt[4];
    __builtin_nontemporal_store(o, reinterpret_cast<f32x4*>(out + base + 4 * 256));
    o.x = s5.x + add0 + rt[5]; o.y = s5.y + add1 + rt[5]; o.z = s5.z + add2 + rt[5]; o.w = s5.w + add3 + rt[5];
    __builtin_nontemporal_store(o, reinterpret_cast<f32x4*>(out + base + 5 * 256));
    o.x = s6.x + add0 + rt[6]; o.y = s6.y + add1 + rt[6]; o.z = s6.z + add2 + rt[6]; o.w = s6.w + add3 + rt[6];
    __builtin_nontemporal_store(o, reinterpret_cast<f32x4*>(out + base + 6 * 256));
    o.x = s7.x + add0 + rt[7]; o.y = s7.y + add1 + rt[7]; o.z = s7.z + add2 + rt[7]; o.w = s7.w + add3 + rt[7];
    __builtin_nontemporal_store(o, reinterpret_cast<f32x4*>(out + base + 7 * 256));
}

extern "C" void kernel_launch(void* const* d_in, const int* in_sizes, int n_in,
                              void* d_out, int out_size, void* d_ws, size_t ws_size,
                              hipStream_t stream) {
    const float* query  = (const float*)d_in[0];  // [2,8,2048,64]
    const float* scores = (const float*)d_in[1];  // [2,8,2048,2048]
    const float* hemb   = (const float*)d_in[2];  // [31,64]
    const float* wemb   = (const float*)d_in[3];  // [31,64]
    const float* temb   = (const float*)d_in[4];  // [15,64]
    float* out = (float*)d_out;

    const int B = in_sizes[0] / (HEADS * QTOK * QDIM);   // = 2
    const int rows = B * HEADS * QTOK;                    // 32768

    relpos_fused_kernel<<<rows / 8, 512, 0, stream>>>(query, scores, hemb, wemb, temb, out);
}